// Round 1
// baseline (558.987 us; speedup 1.0000x reference)
//
#include <hip/hip_runtime.h>
#include <hip/hip_bf16.h>

#define N_NODES 50000
#define N_EDGES 800000
// feature dims fixed at 128 / 131 / 256

// ---------------- ws layout (floats) ----------------
// g:     [50000][128]   @ 0
// sums:  [50000][128]   @ 6,400,000
// cnt:   [50000]        @ 12,800,000
// W1aT:  [128][128]     @ 12,850,000   (k-major: W1aT[k][j] = W1[j][k])
// W1bp:  [128][4]       @ 12,866,384   (per ch: w_ew0, w_ew1, w_ew2, b1)
// W2T:   [256][128]     @ 12,866,896   (k-major)
#define OFF_G     0
#define OFF_SUMS  6400000
#define OFF_CNT   12800000
#define OFF_W1AT  12850000
#define OFF_W1BP  12866384
#define OFF_W2T   12866896

// ---------------- repack weights ----------------
__global__ void repack_kernel(const float* __restrict__ W1, const float* __restrict__ b1,
                              const float* __restrict__ W2,
                              float* __restrict__ W1aT, float* __restrict__ W1bp,
                              float* __restrict__ W2T) {
    int tid = blockIdx.x * 256 + threadIdx.x;
    if (tid < 16384) {                       // W1aT[k][j] = W1[j*131 + k]
        int k = tid >> 7, j = tid & 127;
        W1aT[k * 128 + j] = W1[j * 131 + k];
    }
    if (tid < 128) {                         // W1bp[c] = {W1[c][128..130], b1[c]}
        W1bp[tid * 4 + 0] = W1[tid * 131 + 128];
        W1bp[tid * 4 + 1] = W1[tid * 131 + 129];
        W1bp[tid * 4 + 2] = W1[tid * 131 + 130];
        W1bp[tid * 4 + 3] = b1[tid];
    }
    if (tid < 32768) {                       // W2T[k][j] = W2[j*256 + k]
        int k = tid >> 7, j = tid & 127;
        W2T[k * 128 + j] = W2[j * 256 + k];
    }
}

// ---------------- node pre-projection: g[v] = W1a @ h[v] ----------------
// block: 256 threads, 32 nodes. thread: jg = tid&31 (4 channels), vg = tid>>5 (4 nodes)
__global__ __launch_bounds__(256) void node_proj_kernel(const float* __restrict__ h,
                                                        const float* __restrict__ W1aT,
                                                        float* __restrict__ g) {
    __shared__ float hs[32][128];
    const int tid = threadIdx.x;
    const int block0 = blockIdx.x * 32;

    // stage h tile (float4-coalesced)
    for (int i = tid; i < 32 * 32; i += 256) {
        int v = i >> 5, c4 = i & 31;
        int node = block0 + v;
        float4 val = make_float4(0.f, 0.f, 0.f, 0.f);
        if (node < N_NODES) val = ((const float4*)h)[node * 32 + c4];
        ((float4*)&hs[v][0])[c4] = val;
    }
    __syncthreads();

    const int jg = tid & 31;   // channels jg*4 .. +3
    const int vg = tid >> 5;   // nodes vg*4 .. +3
    const float4* W4 = (const float4*)W1aT;

    float4 acc[4];
    #pragma unroll
    for (int i = 0; i < 4; i++) acc[i] = make_float4(0.f, 0.f, 0.f, 0.f);

    for (int k4 = 0; k4 < 32; k4++) {
        float4 w0 = W4[(k4 * 4 + 0) * 32 + jg];
        float4 w1 = W4[(k4 * 4 + 1) * 32 + jg];
        float4 w2 = W4[(k4 * 4 + 2) * 32 + jg];
        float4 w3 = W4[(k4 * 4 + 3) * 32 + jg];
        #pragma unroll
        for (int i = 0; i < 4; i++) {
            float4 hv = ((const float4*)&hs[vg * 4 + i][0])[k4];
            acc[i].x = fmaf(w0.x, hv.x, acc[i].x);
            acc[i].y = fmaf(w0.y, hv.x, acc[i].y);
            acc[i].z = fmaf(w0.z, hv.x, acc[i].z);
            acc[i].w = fmaf(w0.w, hv.x, acc[i].w);
            acc[i].x = fmaf(w1.x, hv.y, acc[i].x);
            acc[i].y = fmaf(w1.y, hv.y, acc[i].y);
            acc[i].z = fmaf(w1.z, hv.y, acc[i].z);
            acc[i].w = fmaf(w1.w, hv.y, acc[i].w);
            acc[i].x = fmaf(w2.x, hv.z, acc[i].x);
            acc[i].y = fmaf(w2.y, hv.z, acc[i].y);
            acc[i].z = fmaf(w2.z, hv.z, acc[i].z);
            acc[i].w = fmaf(w2.w, hv.z, acc[i].w);
            acc[i].x = fmaf(w3.x, hv.w, acc[i].x);
            acc[i].y = fmaf(w3.y, hv.w, acc[i].y);
            acc[i].z = fmaf(w3.z, hv.w, acc[i].z);
            acc[i].w = fmaf(w3.w, hv.w, acc[i].w);
        }
    }
    #pragma unroll
    for (int i = 0; i < 4; i++) {
        int node = block0 + vg * 4 + i;
        if (node < N_NODES) ((float4*)g)[node * 32 + jg] = acc[i];
    }
}

// ---------------- edge kernel: scatter-add leaky(g[src] + W1b@ew + b1) into sums[dst] ----------------
#define EDGES_PER_BLOCK 8
__global__ __launch_bounds__(256) void edge_kernel(const float* __restrict__ g,
                                                   const int* __restrict__ esrc,
                                                   const int* __restrict__ edst,
                                                   const float* __restrict__ ew,
                                                   const float* __restrict__ W1bp,
                                                   float* __restrict__ sums,
                                                   float* __restrict__ cnt) {
    const int c = threadIdx.x & 127;
    const int sub = threadIdx.x >> 7;     // 0 or 1
    const int e0 = blockIdx.x * EDGES_PER_BLOCK;
    const float4 wb = ((const float4*)W1bp)[c];   // {w_ew0, w_ew1, w_ew2, b1}

    #pragma unroll
    for (int i = 0; i < EDGES_PER_BLOCK / 2; i++) {
        int e = e0 + i * 2 + sub;
        if (e < N_EDGES) {
            int src = esrc[e];
            int dst = edst[e];
            float w0 = ew[e * 3 + 0];
            float w1 = ew[e * 3 + 1];
            float w2 = ew[e * 3 + 2];
            float t = g[src * 128 + c];
            t = fmaf(wb.x, w0, t);
            t = fmaf(wb.y, w1, t);
            t = fmaf(wb.z, w2, t);
            t += wb.w;
            t = (t >= 0.f) ? t : 0.01f * t;
            atomicAdd(&sums[dst * 128 + c], t);
            if (c == 0) atomicAdd(&cnt[dst], 1.0f);
        }
    }
}

// ---------------- final: out = relu(W2 @ concat(h, sums/max(cnt,1)) + b2) ----------------
__global__ __launch_bounds__(256) void final_kernel(const float* __restrict__ h,
                                                    const float* __restrict__ sums,
                                                    const float* __restrict__ cnt,
                                                    const float* __restrict__ W2T,
                                                    const float* __restrict__ b2,
                                                    float* __restrict__ out) {
    __shared__ float hs[32][256];
    const int tid = threadIdx.x;
    const int block0 = blockIdx.x * 32;

    // stage h part
    for (int i = tid; i < 32 * 32; i += 256) {
        int v = i >> 5, c4 = i & 31;
        int node = block0 + v;
        float4 val = make_float4(0.f, 0.f, 0.f, 0.f);
        if (node < N_NODES) val = ((const float4*)h)[node * 32 + c4];
        ((float4*)&hs[v][0])[c4] = val;
    }
    // stage h_N part (mean of aggregated messages)
    for (int i = tid; i < 32 * 32; i += 256) {
        int v = i >> 5, c4 = i & 31;
        int node = block0 + v;
        float4 val = make_float4(0.f, 0.f, 0.f, 0.f);
        if (node < N_NODES) {
            float inv = 1.0f / fmaxf(cnt[node], 1.0f);
            float4 s = ((const float4*)sums)[node * 32 + c4];
            val = make_float4(s.x * inv, s.y * inv, s.z * inv, s.w * inv);
        }
        ((float4*)&hs[v][0])[32 + c4] = val;
    }
    __syncthreads();

    const int jg = tid & 31;
    const int vg = tid >> 5;
    const float4* W4 = (const float4*)W2T;
    const float4 bias = ((const float4*)b2)[jg];

    float4 acc[4];
    #pragma unroll
    for (int i = 0; i < 4; i++) acc[i] = bias;

    for (int k4 = 0; k4 < 64; k4++) {
        float4 w0 = W4[(k4 * 4 + 0) * 32 + jg];
        float4 w1 = W4[(k4 * 4 + 1) * 32 + jg];
        float4 w2 = W4[(k4 * 4 + 2) * 32 + jg];
        float4 w3 = W4[(k4 * 4 + 3) * 32 + jg];
        #pragma unroll
        for (int i = 0; i < 4; i++) {
            float4 hv = ((const float4*)&hs[vg * 4 + i][0])[k4];
            acc[i].x = fmaf(w0.x, hv.x, acc[i].x);
            acc[i].y = fmaf(w0.y, hv.x, acc[i].y);
            acc[i].z = fmaf(w0.z, hv.x, acc[i].z);
            acc[i].w = fmaf(w0.w, hv.x, acc[i].w);
            acc[i].x = fmaf(w1.x, hv.y, acc[i].x);
            acc[i].y = fmaf(w1.y, hv.y, acc[i].y);
            acc[i].z = fmaf(w1.z, hv.y, acc[i].z);
            acc[i].w = fmaf(w1.w, hv.y, acc[i].w);
            acc[i].x = fmaf(w2.x, hv.z, acc[i].x);
            acc[i].y = fmaf(w2.y, hv.z, acc[i].y);
            acc[i].z = fmaf(w2.z, hv.z, acc[i].z);
            acc[i].w = fmaf(w2.w, hv.z, acc[i].w);
            acc[i].x = fmaf(w3.x, hv.w, acc[i].x);
            acc[i].y = fmaf(w3.y, hv.w, acc[i].y);
            acc[i].z = fmaf(w3.z, hv.w, acc[i].z);
            acc[i].w = fmaf(w3.w, hv.w, acc[i].w);
        }
    }
    #pragma unroll
    for (int i = 0; i < 4; i++) {
        int node = block0 + vg * 4 + i;
        if (node < N_NODES) {
            float4 r;
            r.x = fmaxf(acc[i].x, 0.f);
            r.y = fmaxf(acc[i].y, 0.f);
            r.z = fmaxf(acc[i].z, 0.f);
            r.w = fmaxf(acc[i].w, 0.f);
            ((float4*)out)[node * 32 + jg] = r;
        }
    }
}

extern "C" void kernel_launch(void* const* d_in, const int* in_sizes, int n_in,
                              void* d_out, int out_size, void* d_ws, size_t ws_size,
                              hipStream_t stream) {
    const float* h    = (const float*)d_in[0];
    const int*   esrc = (const int*)d_in[1];
    const int*   edst = (const int*)d_in[2];
    const float* ew   = (const float*)d_in[3];
    const float* W1   = (const float*)d_in[4];
    const float* b1   = (const float*)d_in[5];
    const float* W2   = (const float*)d_in[6];
    const float* b2   = (const float*)d_in[7];
    float* out = (float*)d_out;
    float* ws  = (float*)d_ws;

    float* g    = ws + OFF_G;
    float* sums = ws + OFF_SUMS;
    float* cnt  = ws + OFF_CNT;
    float* W1aT = ws + OFF_W1AT;
    float* W1bp = ws + OFF_W1BP;
    float* W2T  = ws + OFF_W2T;

    // 1. repack weights
    repack_kernel<<<128, 256, 0, stream>>>(W1, b1, W2, W1aT, W1bp, W2T);

    // 2. zero sums + cnt (ws is poisoned 0xAA every call)
    hipMemsetAsync(sums, 0, (size_t)(6400000 + 50000) * sizeof(float), stream);

    // 3. node pre-projection
    node_proj_kernel<<<(N_NODES + 31) / 32, 256, 0, stream>>>(h, W1aT, g);

    // 4. edge scatter
    edge_kernel<<<(N_EDGES + EDGES_PER_BLOCK - 1) / EDGES_PER_BLOCK, 256, 0, stream>>>(
        g, esrc, edst, ew, W1bp, sums, cnt);

    // 5. final fused GEMM + relu
    final_kernel<<<(N_NODES + 31) / 32, 256, 0, stream>>>(h, sums, cnt, W2T, b2, out);
}

// Round 2
// 487.485 us; speedup vs baseline: 1.1467x; 1.1467x over previous
//
#include <hip/hip_runtime.h>
#include <hip/hip_bf16.h>

#define N_NODES 50000
#define N_EDGES 800000

// ---------------- ws layout (floats) ----------------
// g:     [50000][128]   @ 0
// hN:    [50000][128]   @ 6,400,000   (mean-aggregated messages)
// W1aT:  [128][128]     @ 12,850,000  (k-major: W1aT[k][j] = W1[j][k])
// W1bp:  [128][4]       @ 12,866,384  (per ch: w_ew0, w_ew1, w_ew2, b1)
// W2T:   [256][128]     @ 12,866,896  (k-major)
#define OFF_G     0
#define OFF_HN    6400000
#define OFF_W1AT  12850000
#define OFF_W1BP  12866384
#define OFF_W2T   12866896

// ---------------- d_out scratch layout (floats; dead before final_kernel) ----
// csr:     [800000] float4 records {src_bits, w0, w1, w2}  @ 0
// counts:  int[50000]   @ 3,200,000
// offsets: int[50001]   @ 3,250,000
// cursor:  int[50000]   @ 3,300,008
#define DOUT_CSR     0
#define DOUT_COUNTS  3200000
#define DOUT_OFFSETS 3250000
#define DOUT_CURSOR  3300008

// ---------------- repack weights ----------------
__global__ void repack_kernel(const float* __restrict__ W1, const float* __restrict__ b1,
                              const float* __restrict__ W2,
                              float* __restrict__ W1aT, float* __restrict__ W1bp,
                              float* __restrict__ W2T) {
    int tid = blockIdx.x * 256 + threadIdx.x;
    if (tid < 16384) {                       // W1aT[k][j] = W1[j*131 + k]
        int k = tid >> 7, j = tid & 127;
        W1aT[k * 128 + j] = W1[j * 131 + k];
    }
    if (tid < 128) {                         // W1bp[c] = {W1[c][128..130], b1[c]}
        W1bp[tid * 4 + 0] = W1[tid * 131 + 128];
        W1bp[tid * 4 + 1] = W1[tid * 131 + 129];
        W1bp[tid * 4 + 2] = W1[tid * 131 + 130];
        W1bp[tid * 4 + 3] = b1[tid];
    }
    if (tid < 32768) {                       // W2T[k][j] = W2[j*256 + k]
        int k = tid >> 7, j = tid & 127;
        W2T[k * 128 + j] = W2[j * 256 + k];
    }
}

// ---------------- CSR phase A: histogram of edge_dst ----------------
__global__ void hist_kernel(const int* __restrict__ edst, int* __restrict__ counts) {
    int e = blockIdx.x * 256 + threadIdx.x;
    if (e < N_EDGES) atomicAdd(&counts[edst[e]], 1);
}

// ---------------- CSR phase A2: exclusive scan (single block) ----------------
__global__ __launch_bounds__(1024) void scan_kernel(const int* __restrict__ counts,
                                                    int* __restrict__ offsets,
                                                    int* __restrict__ cursor) {
    __shared__ int part[1024];
    const int t = threadIdx.x;
    const int CH = 49;                        // 49*1024 = 50176 >= 50000
    const int base = t * CH;
    int s = 0;
    for (int i = 0; i < CH; i++) {
        int idx = base + i;
        if (idx < N_NODES) s += counts[idx];
    }
    part[t] = s;
    __syncthreads();
    for (int off = 1; off < 1024; off <<= 1) {   // Hillis-Steele inclusive scan
        int v = part[t];
        int add = (t >= off) ? part[t - off] : 0;
        __syncthreads();
        part[t] = v + add;
        __syncthreads();
    }
    int run = (t == 0) ? 0 : part[t - 1];        // exclusive prefix of this chunk
    for (int i = 0; i < CH; i++) {
        int idx = base + i;
        if (idx < N_NODES) {
            offsets[idx] = run;
            cursor[idx] = run;
            run += counts[idx];
        }
    }
    if (t == 1023) offsets[N_NODES] = run;       // == N_EDGES (tail chunks add 0)
}

// ---------------- CSR phase B: scatter 16B edge records ----------------
__global__ void build_csr_kernel(const int* __restrict__ esrc, const int* __restrict__ edst,
                                 const float* __restrict__ ew,
                                 int* __restrict__ cursor, float4* __restrict__ csr) {
    int e = blockIdx.x * 256 + threadIdx.x;
    if (e < N_EDGES) {
        int dst = edst[e];
        int pos = atomicAdd(&cursor[dst], 1);
        float4 r;
        r.x = __int_as_float(esrc[e]);
        r.y = ew[e * 3 + 0];
        r.z = ew[e * 3 + 1];
        r.w = ew[e * 3 + 2];
        csr[pos] = r;
    }
}

// ---------------- node pre-projection: g[v] = W1a @ h[v] ----------------
__global__ __launch_bounds__(256) void node_proj_kernel(const float* __restrict__ h,
                                                        const float* __restrict__ W1aT,
                                                        float* __restrict__ g) {
    __shared__ float hs[32][128];
    const int tid = threadIdx.x;
    const int block0 = blockIdx.x * 32;

    for (int i = tid; i < 32 * 32; i += 256) {
        int v = i >> 5, c4 = i & 31;
        int node = block0 + v;
        float4 val = make_float4(0.f, 0.f, 0.f, 0.f);
        if (node < N_NODES) val = ((const float4*)h)[node * 32 + c4];
        ((float4*)&hs[v][0])[c4] = val;
    }
    __syncthreads();

    const int jg = tid & 31;
    const int vg = tid >> 5;
    const float4* W4 = (const float4*)W1aT;

    float4 acc[4];
    #pragma unroll
    for (int i = 0; i < 4; i++) acc[i] = make_float4(0.f, 0.f, 0.f, 0.f);

    for (int k4 = 0; k4 < 32; k4++) {
        float4 w0 = W4[(k4 * 4 + 0) * 32 + jg];
        float4 w1 = W4[(k4 * 4 + 1) * 32 + jg];
        float4 w2 = W4[(k4 * 4 + 2) * 32 + jg];
        float4 w3 = W4[(k4 * 4 + 3) * 32 + jg];
        #pragma unroll
        for (int i = 0; i < 4; i++) {
            float4 hv = ((const float4*)&hs[vg * 4 + i][0])[k4];
            acc[i].x = fmaf(w0.x, hv.x, acc[i].x);
            acc[i].y = fmaf(w0.y, hv.x, acc[i].y);
            acc[i].z = fmaf(w0.z, hv.x, acc[i].z);
            acc[i].w = fmaf(w0.w, hv.x, acc[i].w);
            acc[i].x = fmaf(w1.x, hv.y, acc[i].x);
            acc[i].y = fmaf(w1.y, hv.y, acc[i].y);
            acc[i].z = fmaf(w1.z, hv.y, acc[i].z);
            acc[i].w = fmaf(w1.w, hv.y, acc[i].w);
            acc[i].x = fmaf(w2.x, hv.z, acc[i].x);
            acc[i].y = fmaf(w2.y, hv.z, acc[i].y);
            acc[i].z = fmaf(w2.z, hv.z, acc[i].z);
            acc[i].w = fmaf(w2.w, hv.z, acc[i].w);
            acc[i].x = fmaf(w3.x, hv.w, acc[i].x);
            acc[i].y = fmaf(w3.y, hv.w, acc[i].y);
            acc[i].z = fmaf(w3.z, hv.w, acc[i].z);
            acc[i].w = fmaf(w3.w, hv.w, acc[i].w);
        }
    }
    #pragma unroll
    for (int i = 0; i < 4; i++) {
        int node = block0 + vg * 4 + i;
        if (node < N_NODES) ((float4*)g)[node * 32 + jg] = acc[i];
    }
}

// ---------------- aggregation: one wave per dst node, no float atomics --------
// lane owns channels {2*lane, 2*lane+1}; per edge: 16B broadcast record read +
// coalesced 512B gather of g[src]; accumulate in regs; one float2 store of mean.
__global__ __launch_bounds__(256) void agg_kernel(const float* __restrict__ g,
                                                  const float4* __restrict__ csr,
                                                  const int* __restrict__ offsets,
                                                  const float* __restrict__ W1bp,
                                                  float* __restrict__ hN) {
    const int wave = threadIdx.x >> 6;
    const int lane = threadIdx.x & 63;
    const int v = blockIdx.x * 4 + wave;
    if (v >= N_NODES) return;

    const int beg = offsets[v];
    const int end = offsets[v + 1];
    const float4 wb0 = ((const float4*)W1bp)[2 * lane];
    const float4 wb1 = ((const float4*)W1bp)[2 * lane + 1];

    float a0 = 0.f, a1 = 0.f;
    for (int i = beg; i < end; i++) {
        float4 r = csr[i];                       // same addr across wave: broadcast
        int src = __float_as_int(r.x);
        float2 gv = ((const float2*)g)[src * 64 + lane];   // coalesced 512B/wave
        float t0 = fmaf(wb0.x, r.y, gv.x);
        t0 = fmaf(wb0.y, r.z, t0);
        t0 = fmaf(wb0.z, r.w, t0);
        t0 += wb0.w;
        t0 = (t0 >= 0.f) ? t0 : 0.01f * t0;
        a0 += t0;
        float t1 = fmaf(wb1.x, r.y, gv.y);
        t1 = fmaf(wb1.y, r.z, t1);
        t1 = fmaf(wb1.z, r.w, t1);
        t1 += wb1.w;
        t1 = (t1 >= 0.f) ? t1 : 0.01f * t1;
        a1 += t1;
    }
    int deg = end - beg;
    float inv = 1.0f / (float)((deg > 0) ? deg : 1);
    ((float2*)hN)[v * 64 + lane] = make_float2(a0 * inv, a1 * inv);
}

// ---------------- final: out = relu(W2 @ concat(h, hN) + b2) ----------------
__global__ __launch_bounds__(256) void final_kernel(const float* __restrict__ h,
                                                    const float* __restrict__ hN,
                                                    const float* __restrict__ W2T,
                                                    const float* __restrict__ b2,
                                                    float* __restrict__ out) {
    __shared__ float hs[32][256];
    const int tid = threadIdx.x;
    const int block0 = blockIdx.x * 32;

    for (int i = tid; i < 32 * 32; i += 256) {
        int v = i >> 5, c4 = i & 31;
        int node = block0 + v;
        float4 val = make_float4(0.f, 0.f, 0.f, 0.f);
        if (node < N_NODES) val = ((const float4*)h)[node * 32 + c4];
        ((float4*)&hs[v][0])[c4] = val;
    }
    for (int i = tid; i < 32 * 32; i += 256) {
        int v = i >> 5, c4 = i & 31;
        int node = block0 + v;
        float4 val = make_float4(0.f, 0.f, 0.f, 0.f);
        if (node < N_NODES) val = ((const float4*)hN)[node * 32 + c4];
        ((float4*)&hs[v][0])[32 + c4] = val;
    }
    __syncthreads();

    const int jg = tid & 31;
    const int vg = tid >> 5;
    const float4* W4 = (const float4*)W2T;
    const float4 bias = ((const float4*)b2)[jg];

    float4 acc[4];
    #pragma unroll
    for (int i = 0; i < 4; i++) acc[i] = bias;

    for (int k4 = 0; k4 < 64; k4++) {
        float4 w0 = W4[(k4 * 4 + 0) * 32 + jg];
        float4 w1 = W4[(k4 * 4 + 1) * 32 + jg];
        float4 w2 = W4[(k4 * 4 + 2) * 32 + jg];
        float4 w3 = W4[(k4 * 4 + 3) * 32 + jg];
        #pragma unroll
        for (int i = 0; i < 4; i++) {
            float4 hv = ((const float4*)&hs[vg * 4 + i][0])[k4];
            acc[i].x = fmaf(w0.x, hv.x, acc[i].x);
            acc[i].y = fmaf(w0.y, hv.x, acc[i].y);
            acc[i].z = fmaf(w0.z, hv.x, acc[i].z);
            acc[i].w = fmaf(w0.w, hv.x, acc[i].w);
            acc[i].x = fmaf(w1.x, hv.y, acc[i].x);
            acc[i].y = fmaf(w1.y, hv.y, acc[i].y);
            acc[i].z = fmaf(w1.z, hv.y, acc[i].z);
            acc[i].w = fmaf(w1.w, hv.y, acc[i].w);
            acc[i].x = fmaf(w2.x, hv.z, acc[i].x);
            acc[i].y = fmaf(w2.y, hv.z, acc[i].y);
            acc[i].z = fmaf(w2.z, hv.z, acc[i].z);
            acc[i].w = fmaf(w2.w, hv.z, acc[i].w);
            acc[i].x = fmaf(w3.x, hv.w, acc[i].x);
            acc[i].y = fmaf(w3.y, hv.w, acc[i].y);
            acc[i].z = fmaf(w3.z, hv.w, acc[i].z);
            acc[i].w = fmaf(w3.w, hv.w, acc[i].w);
        }
    }
    #pragma unroll
    for (int i = 0; i < 4; i++) {
        int node = block0 + vg * 4 + i;
        if (node < N_NODES) {
            float4 r;
            r.x = fmaxf(acc[i].x, 0.f);
            r.y = fmaxf(acc[i].y, 0.f);
            r.z = fmaxf(acc[i].z, 0.f);
            r.w = fmaxf(acc[i].w, 0.f);
            ((float4*)out)[node * 32 + jg] = r;
        }
    }
}

extern "C" void kernel_launch(void* const* d_in, const int* in_sizes, int n_in,
                              void* d_out, int out_size, void* d_ws, size_t ws_size,
                              hipStream_t stream) {
    const float* h    = (const float*)d_in[0];
    const int*   esrc = (const int*)d_in[1];
    const int*   edst = (const int*)d_in[2];
    const float* ew   = (const float*)d_in[3];
    const float* W1   = (const float*)d_in[4];
    const float* b1   = (const float*)d_in[5];
    const float* W2   = (const float*)d_in[6];
    const float* b2   = (const float*)d_in[7];
    float* out = (float*)d_out;
    float* ws  = (float*)d_ws;

    float* g    = ws + OFF_G;
    float* hN   = ws + OFF_HN;
    float* W1aT = ws + OFF_W1AT;
    float* W1bp = ws + OFF_W1BP;
    float* W2T  = ws + OFF_W2T;

    // scratch carved out of d_out (fully dead before final_kernel writes out)
    float4* csr    = (float4*)((float*)d_out + DOUT_CSR);
    int*    counts = (int*)((float*)d_out + DOUT_COUNTS);
    int*    offs   = (int*)((float*)d_out + DOUT_OFFSETS);
    int*    cursor = (int*)((float*)d_out + DOUT_CURSOR);

    // 1. repack weights
    repack_kernel<<<128, 256, 0, stream>>>(W1, b1, W2, W1aT, W1bp, W2T);

    // 2. CSR build: zero counts, histogram, scan, scatter records
    hipMemsetAsync(counts, 0, (size_t)N_NODES * sizeof(int), stream);
    hist_kernel<<<(N_EDGES + 255) / 256, 256, 0, stream>>>(edst, counts);
    scan_kernel<<<1, 1024, 0, stream>>>(counts, offs, cursor);
    build_csr_kernel<<<(N_EDGES + 255) / 256, 256, 0, stream>>>(esrc, edst, ew, cursor, csr);

    // 3. node pre-projection
    node_proj_kernel<<<(N_NODES + 31) / 32, 256, 0, stream>>>(h, W1aT, g);

    // 4. aggregation (wave per dst, no float atomics)
    agg_kernel<<<(N_NODES + 3) / 4, 256, 0, stream>>>(g, csr, offs, W1bp, hN);

    // 5. final fused GEMM + relu
    final_kernel<<<(N_NODES + 31) / 32, 256, 0, stream>>>(h, hN, W2T, b2, out);
}

// Round 3
// 367.005 us; speedup vs baseline: 1.5231x; 1.3283x over previous
//
#include <hip/hip_runtime.h>
#include <hip/hip_bf16.h>

#define N_NODES 50000
#define N_EDGES 800000
#define SCAN_BLOCKS 196   // ceil(50000 / 256)

// ---------------- ws layout (floats) ----------------
// g:     [50000][128]   @ 0
// hN:    [50000][128]   @ 6,400,000   (mean-aggregated messages)
// W1aT:  [128][128]     @ 12,850,000  (k-major: W1aT[k][j] = W1[j][k])
// W1bp:  [128][4]       @ 12,866,384  (per ch: w_ew0, w_ew1, w_ew2, b1)
// W2T:   [256][128]     @ 12,866,896  (k-major)
#define OFF_G     0
#define OFF_HN    6400000
#define OFF_W1AT  12850000
#define OFF_W1BP  12866384
#define OFF_W2T   12866896

// ---------------- d_out scratch layout (floats; dead before final_kernel) ----
// csr:       [800000] float4 records {src_bits, w0, w1, w2}  @ 0
// counts:    int[50000]   @ 3,200,000
// offsets:   int[50001]   @ 3,250,000
// cursor:    int[50000]   @ 3,300,008
// blockSums: int[196]     @ 3,350,008
#define DOUT_CSR       0
#define DOUT_COUNTS    3200000
#define DOUT_OFFSETS   3250000
#define DOUT_CURSOR    3300008
#define DOUT_BLKSUMS   3350008

// ---------------- repack weights ----------------
__global__ void repack_kernel(const float* __restrict__ W1, const float* __restrict__ b1,
                              const float* __restrict__ W2,
                              float* __restrict__ W1aT, float* __restrict__ W1bp,
                              float* __restrict__ W2T) {
    int tid = blockIdx.x * 256 + threadIdx.x;
    if (tid < 16384) {                       // W1aT[k][j] = W1[j*131 + k]
        int k = tid >> 7, j = tid & 127;
        W1aT[k * 128 + j] = W1[j * 131 + k];
    }
    if (tid < 128) {                         // W1bp[c] = {W1[c][128..130], b1[c]}
        W1bp[tid * 4 + 0] = W1[tid * 131 + 128];
        W1bp[tid * 4 + 1] = W1[tid * 131 + 129];
        W1bp[tid * 4 + 2] = W1[tid * 131 + 130];
        W1bp[tid * 4 + 3] = b1[tid];
    }
    if (tid < 32768) {                       // W2T[k][j] = W2[j*256 + k]
        int k = tid >> 7, j = tid & 127;
        W2T[k * 128 + j] = W2[j * 256 + k];
    }
}

// ---------------- CSR phase A: histogram of edge_dst ----------------
__global__ void hist_kernel(const int* __restrict__ edst, int* __restrict__ counts) {
    int e = blockIdx.x * 256 + threadIdx.x;
    if (e < N_EDGES) atomicAdd(&counts[edst[e]], 1);
}

// ---------------- parallel scan, phase A: per-block scan + block totals ------
__global__ __launch_bounds__(256) void scanA_kernel(const int* __restrict__ counts,
                                                    int* __restrict__ offsets,
                                                    int* __restrict__ blockSums) {
    __shared__ int sd[256];
    const int t = threadIdx.x, b = blockIdx.x;
    const int idx = b * 256 + t;
    int v = (idx < N_NODES) ? counts[idx] : 0;
    sd[t] = v;
    __syncthreads();
    for (int off = 1; off < 256; off <<= 1) {    // Hillis-Steele inclusive
        int x = sd[t];
        int add = (t >= off) ? sd[t - off] : 0;
        __syncthreads();
        sd[t] = x + add;
        __syncthreads();
    }
    if (idx < N_NODES) offsets[idx] = sd[t] - v;  // within-block exclusive
    if (t == 255) blockSums[b] = sd[255];
}

// ---------------- parallel scan, phase B: add block prefix ----------------
__global__ __launch_bounds__(256) void scanB_kernel(int* __restrict__ offsets,
                                                    const int* __restrict__ blockSums,
                                                    int* __restrict__ cursor) {
    __shared__ int sd[256];
    const int t = threadIdx.x, b = blockIdx.x;
    sd[t] = (t < SCAN_BLOCKS) ? blockSums[t] : 0;
    __syncthreads();
    for (int off = 1; off < 256; off <<= 1) {    // scan the 196 block totals
        int x = sd[t];
        int add = (t >= off) ? sd[t - off] : 0;
        __syncthreads();
        sd[t] = x + add;
        __syncthreads();
    }
    const int prefix = (b == 0) ? 0 : sd[b - 1];
    const int idx = b * 256 + t;
    if (idx < N_NODES) {
        int o = offsets[idx] + prefix;
        offsets[idx] = o;
        cursor[idx] = o;
    }
    if (b == SCAN_BLOCKS - 1 && t == 255) offsets[N_NODES] = sd[SCAN_BLOCKS - 1];
}

// ---------------- CSR phase B: scatter 16B edge records ----------------
__global__ void build_csr_kernel(const int* __restrict__ esrc, const int* __restrict__ edst,
                                 const float* __restrict__ ew,
                                 int* __restrict__ cursor, float4* __restrict__ csr) {
    int e = blockIdx.x * 256 + threadIdx.x;
    if (e < N_EDGES) {
        int dst = edst[e];
        int pos = atomicAdd(&cursor[dst], 1);
        float4 r;
        r.x = __int_as_float(esrc[e]);
        r.y = ew[e * 3 + 0];
        r.z = ew[e * 3 + 1];
        r.w = ew[e * 3 + 2];
        csr[pos] = r;
    }
}

// ---------------- node pre-projection: g[v] = W1a @ h[v] ----------------
__global__ __launch_bounds__(256) void node_proj_kernel(const float* __restrict__ h,
                                                        const float* __restrict__ W1aT,
                                                        float* __restrict__ g) {
    __shared__ float hs[32][128];
    const int tid = threadIdx.x;
    const int block0 = blockIdx.x * 32;

    for (int i = tid; i < 32 * 32; i += 256) {
        int v = i >> 5, c4 = i & 31;
        int node = block0 + v;
        float4 val = make_float4(0.f, 0.f, 0.f, 0.f);
        if (node < N_NODES) val = ((const float4*)h)[node * 32 + c4];
        ((float4*)&hs[v][0])[c4] = val;
    }
    __syncthreads();

    const int jg = tid & 31;
    const int vg = tid >> 5;
    const float4* W4 = (const float4*)W1aT;

    float4 acc[4];
    #pragma unroll
    for (int i = 0; i < 4; i++) acc[i] = make_float4(0.f, 0.f, 0.f, 0.f);

    for (int k4 = 0; k4 < 32; k4++) {
        float4 w0 = W4[(k4 * 4 + 0) * 32 + jg];
        float4 w1 = W4[(k4 * 4 + 1) * 32 + jg];
        float4 w2 = W4[(k4 * 4 + 2) * 32 + jg];
        float4 w3 = W4[(k4 * 4 + 3) * 32 + jg];
        #pragma unroll
        for (int i = 0; i < 4; i++) {
            float4 hv = ((const float4*)&hs[vg * 4 + i][0])[k4];
            acc[i].x = fmaf(w0.x, hv.x, acc[i].x);
            acc[i].y = fmaf(w0.y, hv.x, acc[i].y);
            acc[i].z = fmaf(w0.z, hv.x, acc[i].z);
            acc[i].w = fmaf(w0.w, hv.x, acc[i].w);
            acc[i].x = fmaf(w1.x, hv.y, acc[i].x);
            acc[i].y = fmaf(w1.y, hv.y, acc[i].y);
            acc[i].z = fmaf(w1.z, hv.y, acc[i].z);
            acc[i].w = fmaf(w1.w, hv.y, acc[i].w);
            acc[i].x = fmaf(w2.x, hv.z, acc[i].x);
            acc[i].y = fmaf(w2.y, hv.z, acc[i].y);
            acc[i].z = fmaf(w2.z, hv.z, acc[i].z);
            acc[i].w = fmaf(w2.w, hv.z, acc[i].w);
            acc[i].x = fmaf(w3.x, hv.w, acc[i].x);
            acc[i].y = fmaf(w3.y, hv.w, acc[i].y);
            acc[i].z = fmaf(w3.z, hv.w, acc[i].z);
            acc[i].w = fmaf(w3.w, hv.w, acc[i].w);
        }
    }
    #pragma unroll
    for (int i = 0; i < 4; i++) {
        int node = block0 + vg * 4 + i;
        if (node < N_NODES) ((float4*)g)[node * 32 + jg] = acc[i];
    }
}

// ---------------- aggregation: one wave per dst node, no float atomics --------
__global__ __launch_bounds__(256) void agg_kernel(const float* __restrict__ g,
                                                  const float4* __restrict__ csr,
                                                  const int* __restrict__ offsets,
                                                  const float* __restrict__ W1bp,
                                                  float* __restrict__ hN) {
    const int wave = threadIdx.x >> 6;
    const int lane = threadIdx.x & 63;
    const int v = blockIdx.x * 4 + wave;
    if (v >= N_NODES) return;

    const int beg = offsets[v];
    const int end = offsets[v + 1];
    const float4 wb0 = ((const float4*)W1bp)[2 * lane];
    const float4 wb1 = ((const float4*)W1bp)[2 * lane + 1];

    float a0 = 0.f, a1 = 0.f;
    for (int i = beg; i < end; i++) {
        float4 r = csr[i];                       // same addr across wave: broadcast
        int src = __float_as_int(r.x);
        float2 gv = ((const float2*)g)[src * 64 + lane];   // coalesced 512B/wave
        float t0 = fmaf(wb0.x, r.y, gv.x);
        t0 = fmaf(wb0.y, r.z, t0);
        t0 = fmaf(wb0.z, r.w, t0);
        t0 += wb0.w;
        t0 = (t0 >= 0.f) ? t0 : 0.01f * t0;
        a0 += t0;
        float t1 = fmaf(wb1.x, r.y, gv.y);
        t1 = fmaf(wb1.y, r.z, t1);
        t1 = fmaf(wb1.z, r.w, t1);
        t1 += wb1.w;
        t1 = (t1 >= 0.f) ? t1 : 0.01f * t1;
        a1 += t1;
    }
    int deg = end - beg;
    float inv = 1.0f / (float)((deg > 0) ? deg : 1);
    ((float2*)hN)[v * 64 + lane] = make_float2(a0 * inv, a1 * inv);
}

// ---------------- final: out = relu(W2 @ concat(h, hN) + b2) ----------------
__global__ __launch_bounds__(256) void final_kernel(const float* __restrict__ h,
                                                    const float* __restrict__ hN,
                                                    const float* __restrict__ W2T,
                                                    const float* __restrict__ b2,
                                                    float* __restrict__ out) {
    __shared__ float hs[32][256];
    const int tid = threadIdx.x;
    const int block0 = blockIdx.x * 32;

    for (int i = tid; i < 32 * 32; i += 256) {
        int v = i >> 5, c4 = i & 31;
        int node = block0 + v;
        float4 val = make_float4(0.f, 0.f, 0.f, 0.f);
        if (node < N_NODES) val = ((const float4*)h)[node * 32 + c4];
        ((float4*)&hs[v][0])[c4] = val;
    }
    for (int i = tid; i < 32 * 32; i += 256) {
        int v = i >> 5, c4 = i & 31;
        int node = block0 + v;
        float4 val = make_float4(0.f, 0.f, 0.f, 0.f);
        if (node < N_NODES) val = ((const float4*)hN)[node * 32 + c4];
        ((float4*)&hs[v][0])[32 + c4] = val;
    }
    __syncthreads();

    const int jg = tid & 31;
    const int vg = tid >> 5;
    const float4* W4 = (const float4*)W2T;
    const float4 bias = ((const float4*)b2)[jg];

    float4 acc[4];
    #pragma unroll
    for (int i = 0; i < 4; i++) acc[i] = bias;

    for (int k4 = 0; k4 < 64; k4++) {
        float4 w0 = W4[(k4 * 4 + 0) * 32 + jg];
        float4 w1 = W4[(k4 * 4 + 1) * 32 + jg];
        float4 w2 = W4[(k4 * 4 + 2) * 32 + jg];
        float4 w3 = W4[(k4 * 4 + 3) * 32 + jg];
        #pragma unroll
        for (int i = 0; i < 4; i++) {
            float4 hv = ((const float4*)&hs[vg * 4 + i][0])[k4];
            acc[i].x = fmaf(w0.x, hv.x, acc[i].x);
            acc[i].y = fmaf(w0.y, hv.x, acc[i].y);
            acc[i].z = fmaf(w0.z, hv.x, acc[i].z);
            acc[i].w = fmaf(w0.w, hv.x, acc[i].w);
            acc[i].x = fmaf(w1.x, hv.y, acc[i].x);
            acc[i].y = fmaf(w1.y, hv.y, acc[i].y);
            acc[i].z = fmaf(w1.z, hv.y, acc[i].z);
            acc[i].w = fmaf(w1.w, hv.y, acc[i].w);
            acc[i].x = fmaf(w2.x, hv.z, acc[i].x);
            acc[i].y = fmaf(w2.y, hv.z, acc[i].y);
            acc[i].z = fmaf(w2.z, hv.z, acc[i].z);
            acc[i].w = fmaf(w2.w, hv.z, acc[i].w);
            acc[i].x = fmaf(w3.x, hv.w, acc[i].x);
            acc[i].y = fmaf(w3.y, hv.w, acc[i].y);
            acc[i].z = fmaf(w3.z, hv.w, acc[i].z);
            acc[i].w = fmaf(w3.w, hv.w, acc[i].w);
        }
    }
    #pragma unroll
    for (int i = 0; i < 4; i++) {
        int node = block0 + vg * 4 + i;
        if (node < N_NODES) {
            float4 r;
            r.x = fmaxf(acc[i].x, 0.f);
            r.y = fmaxf(acc[i].y, 0.f);
            r.z = fmaxf(acc[i].z, 0.f);
            r.w = fmaxf(acc[i].w, 0.f);
            ((float4*)out)[node * 32 + jg] = r;
        }
    }
}

extern "C" void kernel_launch(void* const* d_in, const int* in_sizes, int n_in,
                              void* d_out, int out_size, void* d_ws, size_t ws_size,
                              hipStream_t stream) {
    const float* h    = (const float*)d_in[0];
    const int*   esrc = (const int*)d_in[1];
    const int*   edst = (const int*)d_in[2];
    const float* ew   = (const float*)d_in[3];
    const float* W1   = (const float*)d_in[4];
    const float* b1   = (const float*)d_in[5];
    const float* W2   = (const float*)d_in[6];
    const float* b2   = (const float*)d_in[7];
    float* out = (float*)d_out;
    float* ws  = (float*)d_ws;

    float* g    = ws + OFF_G;
    float* hN   = ws + OFF_HN;
    float* W1aT = ws + OFF_W1AT;
    float* W1bp = ws + OFF_W1BP;
    float* W2T  = ws + OFF_W2T;

    // scratch carved out of d_out (fully dead before final_kernel writes out)
    float4* csr     = (float4*)((float*)d_out + DOUT_CSR);
    int*    counts  = (int*)((float*)d_out + DOUT_COUNTS);
    int*    offs    = (int*)((float*)d_out + DOUT_OFFSETS);
    int*    cursor  = (int*)((float*)d_out + DOUT_CURSOR);
    int*    blkSums = (int*)((float*)d_out + DOUT_BLKSUMS);

    // 1. repack weights
    repack_kernel<<<128, 256, 0, stream>>>(W1, b1, W2, W1aT, W1bp, W2T);

    // 2. CSR build: zero counts, histogram, parallel scan, scatter records
    hipMemsetAsync(counts, 0, (size_t)N_NODES * sizeof(int), stream);
    hist_kernel<<<(N_EDGES + 255) / 256, 256, 0, stream>>>(edst, counts);
    scanA_kernel<<<SCAN_BLOCKS, 256, 0, stream>>>(counts, offs, blkSums);
    scanB_kernel<<<SCAN_BLOCKS, 256, 0, stream>>>(offs, blkSums, cursor);
    build_csr_kernel<<<(N_EDGES + 255) / 256, 256, 0, stream>>>(esrc, edst, ew, cursor, csr);

    // 3. node pre-projection
    node_proj_kernel<<<(N_NODES + 31) / 32, 256, 0, stream>>>(h, W1aT, g);

    // 4. aggregation (wave per dst, no float atomics)
    agg_kernel<<<(N_NODES + 3) / 4, 256, 0, stream>>>(g, csr, offs, W1bp, hN);

    // 5. final fused GEMM + relu
    final_kernel<<<(N_NODES + 31) / 32, 256, 0, stream>>>(h, hN, W2T, b2, out);
}

// Round 4
// 325.972 us; speedup vs baseline: 1.7148x; 1.1259x over previous
//
#include <hip/hip_runtime.h>
#include <hip/hip_bf16.h>

#define N_NODES 50000
#define N_EDGES 800000
#define SCAN_BLOCKS 196   // ceil(50000 / 256)

// ---------------- ws layout (floats) ----------------
// g (packed bf16x2): uint[50000][64] @ 0        (channels 2q -> low16, 2q+1 -> high16)
// hN:    [50000][128]   @ 6,400,000   (mean-aggregated messages, fp32)
// W1aT:  [128][128]     @ 12,850,000  (k-major: W1aT[k][j] = W1[j][k])
// W1bp:  [128][4]       @ 12,866,384  (per ch: w_ew0, w_ew1, w_ew2, b1)
// W2T:   [256][128]     @ 12,866,896  (k-major)
#define OFF_G     0
#define OFF_HN    6400000
#define OFF_W1AT  12850000
#define OFF_W1BP  12866384
#define OFF_W2T   12866896

// ---------------- d_out scratch layout (floats; dead before final_kernel) ----
#define DOUT_CSR       0
#define DOUT_COUNTS    3200000
#define DOUT_OFFSETS   3250000
#define DOUT_CURSOR    3300008
#define DOUT_BLKSUMS   3350008

__device__ inline unsigned bf16rne(float f) {       // fp32 -> bf16 bits, round-nearest-even
    unsigned u = __float_as_uint(f);
    return (u + 0x7fffu + ((u >> 16) & 1u)) >> 16;
}

// ---------------- repack weights ----------------
__global__ void repack_kernel(const float* __restrict__ W1, const float* __restrict__ b1,
                              const float* __restrict__ W2,
                              float* __restrict__ W1aT, float* __restrict__ W1bp,
                              float* __restrict__ W2T) {
    int tid = blockIdx.x * 256 + threadIdx.x;
    if (tid < 16384) {                       // W1aT[k][j] = W1[j*131 + k]
        int k = tid >> 7, j = tid & 127;
        W1aT[k * 128 + j] = W1[j * 131 + k];
    }
    if (tid < 128) {                         // W1bp[c] = {W1[c][128..130], b1[c]}
        W1bp[tid * 4 + 0] = W1[tid * 131 + 128];
        W1bp[tid * 4 + 1] = W1[tid * 131 + 129];
        W1bp[tid * 4 + 2] = W1[tid * 131 + 130];
        W1bp[tid * 4 + 3] = b1[tid];
    }
    if (tid < 32768) {                       // W2T[k][j] = W2[j*256 + k]
        int k = tid >> 7, j = tid & 127;
        W2T[k * 128 + j] = W2[j * 256 + k];
    }
}

// ---------------- CSR phase A: histogram of edge_dst ----------------
__global__ void hist_kernel(const int* __restrict__ edst, int* __restrict__ counts) {
    int e = blockIdx.x * 256 + threadIdx.x;
    if (e < N_EDGES) atomicAdd(&counts[edst[e]], 1);
}

// ---------------- parallel scan, phase A ----------------
__global__ __launch_bounds__(256) void scanA_kernel(const int* __restrict__ counts,
                                                    int* __restrict__ offsets,
                                                    int* __restrict__ blockSums) {
    __shared__ int sd[256];
    const int t = threadIdx.x, b = blockIdx.x;
    const int idx = b * 256 + t;
    int v = (idx < N_NODES) ? counts[idx] : 0;
    sd[t] = v;
    __syncthreads();
    for (int off = 1; off < 256; off <<= 1) {
        int x = sd[t];
        int add = (t >= off) ? sd[t - off] : 0;
        __syncthreads();
        sd[t] = x + add;
        __syncthreads();
    }
    if (idx < N_NODES) offsets[idx] = sd[t] - v;
    if (t == 255) blockSums[b] = sd[255];
}

// ---------------- parallel scan, phase B ----------------
__global__ __launch_bounds__(256) void scanB_kernel(int* __restrict__ offsets,
                                                    const int* __restrict__ blockSums,
                                                    int* __restrict__ cursor) {
    __shared__ int sd[256];
    const int t = threadIdx.x, b = blockIdx.x;
    sd[t] = (t < SCAN_BLOCKS) ? blockSums[t] : 0;
    __syncthreads();
    for (int off = 1; off < 256; off <<= 1) {
        int x = sd[t];
        int add = (t >= off) ? sd[t - off] : 0;
        __syncthreads();
        sd[t] = x + add;
        __syncthreads();
    }
    const int prefix = (b == 0) ? 0 : sd[b - 1];
    const int idx = b * 256 + t;
    if (idx < N_NODES) {
        int o = offsets[idx] + prefix;
        offsets[idx] = o;
        cursor[idx] = o;
    }
    if (b == SCAN_BLOCKS - 1 && t == 255) offsets[N_NODES] = sd[SCAN_BLOCKS - 1];
}

// ---------------- CSR phase B: scatter 16B edge records ----------------
__global__ void build_csr_kernel(const int* __restrict__ esrc, const int* __restrict__ edst,
                                 const float* __restrict__ ew,
                                 int* __restrict__ cursor, float4* __restrict__ csr) {
    int e = blockIdx.x * 256 + threadIdx.x;
    if (e < N_EDGES) {
        int dst = edst[e];
        int pos = atomicAdd(&cursor[dst], 1);
        float4 r;
        r.x = __int_as_float(esrc[e]);
        r.y = ew[e * 3 + 0];
        r.z = ew[e * 3 + 1];
        r.w = ew[e * 3 + 2];
        csr[pos] = r;
    }
}

// ---------------- node pre-projection: g[v] = W1a @ h[v], packed bf16 out ----
__global__ __launch_bounds__(256) void node_proj_kernel(const float* __restrict__ h,
                                                        const float* __restrict__ W1aT,
                                                        unsigned* __restrict__ g) {
    __shared__ float hs[32][128];
    const int tid = threadIdx.x;
    const int block0 = blockIdx.x * 32;

    for (int i = tid; i < 32 * 32; i += 256) {
        int v = i >> 5, c4 = i & 31;
        int node = block0 + v;
        float4 val = make_float4(0.f, 0.f, 0.f, 0.f);
        if (node < N_NODES) val = ((const float4*)h)[node * 32 + c4];
        ((float4*)&hs[v][0])[c4] = val;
    }
    __syncthreads();

    const int jg = tid & 31;
    const int vg = tid >> 5;
    const float4* W4 = (const float4*)W1aT;

    float4 acc[4];
    #pragma unroll
    for (int i = 0; i < 4; i++) acc[i] = make_float4(0.f, 0.f, 0.f, 0.f);

    for (int k4 = 0; k4 < 32; k4++) {
        float4 w0 = W4[(k4 * 4 + 0) * 32 + jg];
        float4 w1 = W4[(k4 * 4 + 1) * 32 + jg];
        float4 w2 = W4[(k4 * 4 + 2) * 32 + jg];
        float4 w3 = W4[(k4 * 4 + 3) * 32 + jg];
        #pragma unroll
        for (int i = 0; i < 4; i++) {
            float4 hv = ((const float4*)&hs[vg * 4 + i][0])[k4];
            acc[i].x = fmaf(w0.x, hv.x, acc[i].x);
            acc[i].y = fmaf(w0.y, hv.x, acc[i].y);
            acc[i].z = fmaf(w0.z, hv.x, acc[i].z);
            acc[i].w = fmaf(w0.w, hv.x, acc[i].w);
            acc[i].x = fmaf(w1.x, hv.y, acc[i].x);
            acc[i].y = fmaf(w1.y, hv.y, acc[i].y);
            acc[i].z = fmaf(w1.z, hv.y, acc[i].z);
            acc[i].w = fmaf(w1.w, hv.y, acc[i].w);
            acc[i].x = fmaf(w2.x, hv.z, acc[i].x);
            acc[i].y = fmaf(w2.y, hv.z, acc[i].y);
            acc[i].z = fmaf(w2.z, hv.z, acc[i].z);
            acc[i].w = fmaf(w2.w, hv.z, acc[i].w);
            acc[i].x = fmaf(w3.x, hv.w, acc[i].x);
            acc[i].y = fmaf(w3.y, hv.w, acc[i].y);
            acc[i].z = fmaf(w3.z, hv.w, acc[i].z);
            acc[i].w = fmaf(w3.w, hv.w, acc[i].w);
        }
    }
    #pragma unroll
    for (int i = 0; i < 4; i++) {
        int node = block0 + vg * 4 + i;
        if (node < N_NODES) {
            unsigned p0 = bf16rne(acc[i].x) | (bf16rne(acc[i].y) << 16);
            unsigned p1 = bf16rne(acc[i].z) | (bf16rne(acc[i].w) << 16);
            ((uint2*)g)[node * 32 + jg] = make_uint2(p0, p1);
        }
    }
}

// ---------------- aggregation: wave/node, 8 concurrent gather chains ---------
#define AGG_UNROLL 8
__global__ __launch_bounds__(256) void agg_kernel(const unsigned* __restrict__ gb,
                                                  const float4* __restrict__ csr,
                                                  const int* __restrict__ offsets,
                                                  const float* __restrict__ W1bp,
                                                  float* __restrict__ hN) {
    const int wave = threadIdx.x >> 6;
    const int lane = threadIdx.x & 63;
    const int v = blockIdx.x * 4 + wave;
    if (v >= N_NODES) return;

    const int beg = offsets[v];
    const int end = offsets[v + 1];
    const float4 wb0 = ((const float4*)W1bp)[2 * lane];
    const float4 wb1 = ((const float4*)W1bp)[2 * lane + 1];

    float a0 = 0.f, a1 = 0.f;
    for (int i = beg; i < end; i += AGG_UNROLL) {
        const int n = end - i;                      // >= 1, wave-uniform
        float4 r[AGG_UNROLL];
        #pragma unroll
        for (int u = 0; u < AGG_UNROLL; u++) {      // 8 independent broadcast loads
            int idx = i + ((u < n) ? u : 0);
            r[u] = csr[idx];
        }
        unsigned gv[AGG_UNROLL];
        #pragma unroll
        for (int u = 0; u < AGG_UNROLL; u++) {      // 8 independent coalesced gathers
            int src = __float_as_int(r[u].x);
            gv[u] = gb[src * 64 + lane];
        }
        #pragma unroll
        for (int u = 0; u < AGG_UNROLL; u++) {
            if (u < n) {                            // wave-uniform predicate
                float g0 = __uint_as_float(gv[u] << 16);
                float g1 = __uint_as_float(gv[u] & 0xffff0000u);
                float t0 = fmaf(wb0.x, r[u].y, g0);
                t0 = fmaf(wb0.y, r[u].z, t0);
                t0 = fmaf(wb0.z, r[u].w, t0);
                t0 += wb0.w;
                a0 += (t0 >= 0.f) ? t0 : 0.01f * t0;
                float t1 = fmaf(wb1.x, r[u].y, g1);
                t1 = fmaf(wb1.y, r[u].z, t1);
                t1 = fmaf(wb1.z, r[u].w, t1);
                t1 += wb1.w;
                a1 += (t1 >= 0.f) ? t1 : 0.01f * t1;
            }
        }
    }
    int deg = end - beg;
    float inv = 1.0f / (float)((deg > 0) ? deg : 1);
    ((float2*)hN)[v * 64 + lane] = make_float2(a0 * inv, a1 * inv);
}

// ---------------- final: out = relu(W2 @ concat(h, hN) + b2) ----------------
__global__ __launch_bounds__(256) void final_kernel(const float* __restrict__ h,
                                                    const float* __restrict__ hN,
                                                    const float* __restrict__ W2T,
                                                    const float* __restrict__ b2,
                                                    float* __restrict__ out) {
    __shared__ float hs[32][256];
    const int tid = threadIdx.x;
    const int block0 = blockIdx.x * 32;

    for (int i = tid; i < 32 * 32; i += 256) {
        int v = i >> 5, c4 = i & 31;
        int node = block0 + v;
        float4 val = make_float4(0.f, 0.f, 0.f, 0.f);
        if (node < N_NODES) val = ((const float4*)h)[node * 32 + c4];
        ((float4*)&hs[v][0])[c4] = val;
    }
    for (int i = tid; i < 32 * 32; i += 256) {
        int v = i >> 5, c4 = i & 31;
        int node = block0 + v;
        float4 val = make_float4(0.f, 0.f, 0.f, 0.f);
        if (node < N_NODES) val = ((const float4*)hN)[node * 32 + c4];
        ((float4*)&hs[v][0])[32 + c4] = val;
    }
    __syncthreads();

    const int jg = tid & 31;
    const int vg = tid >> 5;
    const float4* W4 = (const float4*)W2T;
    const float4 bias = ((const float4*)b2)[jg];

    float4 acc[4];
    #pragma unroll
    for (int i = 0; i < 4; i++) acc[i] = bias;

    for (int k4 = 0; k4 < 64; k4++) {
        float4 w0 = W4[(k4 * 4 + 0) * 32 + jg];
        float4 w1 = W4[(k4 * 4 + 1) * 32 + jg];
        float4 w2 = W4[(k4 * 4 + 2) * 32 + jg];
        float4 w3 = W4[(k4 * 4 + 3) * 32 + jg];
        #pragma unroll
        for (int i = 0; i < 4; i++) {
            float4 hv = ((const float4*)&hs[vg * 4 + i][0])[k4];
            acc[i].x = fmaf(w0.x, hv.x, acc[i].x);
            acc[i].y = fmaf(w0.y, hv.x, acc[i].y);
            acc[i].z = fmaf(w0.z, hv.x, acc[i].z);
            acc[i].w = fmaf(w0.w, hv.x, acc[i].w);
            acc[i].x = fmaf(w1.x, hv.y, acc[i].x);
            acc[i].y = fmaf(w1.y, hv.y, acc[i].y);
            acc[i].z = fmaf(w1.z, hv.y, acc[i].z);
            acc[i].w = fmaf(w1.w, hv.y, acc[i].w);
            acc[i].x = fmaf(w2.x, hv.z, acc[i].x);
            acc[i].y = fmaf(w2.y, hv.z, acc[i].y);
            acc[i].z = fmaf(w2.z, hv.z, acc[i].z);
            acc[i].w = fmaf(w2.w, hv.z, acc[i].w);
            acc[i].x = fmaf(w3.x, hv.w, acc[i].x);
            acc[i].y = fmaf(w3.y, hv.w, acc[i].y);
            acc[i].z = fmaf(w3.z, hv.w, acc[i].z);
            acc[i].w = fmaf(w3.w, hv.w, acc[i].w);
        }
    }
    #pragma unroll
    for (int i = 0; i < 4; i++) {
        int node = block0 + vg * 4 + i;
        if (node < N_NODES) {
            float4 r;
            r.x = fmaxf(acc[i].x, 0.f);
            r.y = fmaxf(acc[i].y, 0.f);
            r.z = fmaxf(acc[i].z, 0.f);
            r.w = fmaxf(acc[i].w, 0.f);
            ((float4*)out)[node * 32 + jg] = r;
        }
    }
}

extern "C" void kernel_launch(void* const* d_in, const int* in_sizes, int n_in,
                              void* d_out, int out_size, void* d_ws, size_t ws_size,
                              hipStream_t stream) {
    const float* h    = (const float*)d_in[0];
    const int*   esrc = (const int*)d_in[1];
    const int*   edst = (const int*)d_in[2];
    const float* ew   = (const float*)d_in[3];
    const float* W1   = (const float*)d_in[4];
    const float* b1   = (const float*)d_in[5];
    const float* W2   = (const float*)d_in[6];
    const float* b2   = (const float*)d_in[7];
    float* out = (float*)d_out;
    float* ws  = (float*)d_ws;

    unsigned* g  = (unsigned*)(ws + OFF_G);
    float* hN   = ws + OFF_HN;
    float* W1aT = ws + OFF_W1AT;
    float* W1bp = ws + OFF_W1BP;
    float* W2T  = ws + OFF_W2T;

    // scratch carved out of d_out (fully dead before final_kernel writes out)
    float4* csr     = (float4*)((float*)d_out + DOUT_CSR);
    int*    counts  = (int*)((float*)d_out + DOUT_COUNTS);
    int*    offs    = (int*)((float*)d_out + DOUT_OFFSETS);
    int*    cursor  = (int*)((float*)d_out + DOUT_CURSOR);
    int*    blkSums = (int*)((float*)d_out + DOUT_BLKSUMS);

    // 1. repack weights
    repack_kernel<<<128, 256, 0, stream>>>(W1, b1, W2, W1aT, W1bp, W2T);

    // 2. CSR build
    hipMemsetAsync(counts, 0, (size_t)N_NODES * sizeof(int), stream);
    hist_kernel<<<(N_EDGES + 255) / 256, 256, 0, stream>>>(edst, counts);
    scanA_kernel<<<SCAN_BLOCKS, 256, 0, stream>>>(counts, offs, blkSums);
    scanB_kernel<<<SCAN_BLOCKS, 256, 0, stream>>>(offs, blkSums, cursor);
    build_csr_kernel<<<(N_EDGES + 255) / 256, 256, 0, stream>>>(esrc, edst, ew, cursor, csr);

    // 3. node pre-projection (bf16-packed output)
    node_proj_kernel<<<(N_NODES + 31) / 32, 256, 0, stream>>>(h, W1aT, g);

    // 4. aggregation (wave per dst, 8 gather chains in flight)
    agg_kernel<<<(N_NODES + 3) / 4, 256, 0, stream>>>(g, csr, offs, W1bp, hN);

    // 5. final fused GEMM + relu
    final_kernel<<<(N_NODES + 31) / 32, 256, 0, stream>>>(h, hN, W2T, b2, out);
}

// Round 5
// 262.713 us; speedup vs baseline: 2.1277x; 1.2408x over previous
//
#include <hip/hip_runtime.h>
#include <hip/hip_bf16.h>

#define N_NODES 50000
#define N_EDGES 800000
#define SCAN_BLOCKS 196   // ceil(50000 / 256)
#define N_TILES 3125      // 50000 / 16 node tiles (exact)

typedef __attribute__((ext_vector_type(8))) short short8;   // 8 bf16 (4 VGPRs)
typedef __attribute__((ext_vector_type(4))) float f32x4;    // MFMA C/D frag

// ---------------- ws layout (floats) ----------------
// g (packed bf16x2): uint[50000][64] @ 0   (uint l = channels {2l, 2l+1})
// hN:    [50000][128]   @ 6,400,000   (fp32, standard channel order)
// W1bp:  [128][4]       @ 12,866,384  (per ch: w_ew0, w_ew1, w_ew2, b1)
// Bpack1: uint4[4*8*64] @ 12,866,896  (W1a MFMA-B frags, bf16: kt 0..3, nt 0..7)
// Bpack2: uint4[8*8*64] @ 12,875,088  (W2  MFMA-B frags, bf16: kt 0..7, nt 0..7)
#define OFF_G     0
#define OFF_HN    6400000
#define OFF_W1BP  12866384
#define OFF_BP1   12866896
#define OFF_BP2   12875088

// ---------------- d_out scratch layout (floats; dead before final_mfma) ----
#define DOUT_CSR       0
#define DOUT_COUNTS    3200000
#define DOUT_OFFSETS   3250000
#define DOUT_CURSOR    3300008
#define DOUT_BLKSUMS   3350008

__device__ inline unsigned bf16rne(float f) {       // fp32 -> bf16 bits, RNE
    unsigned u = __float_as_uint(f);
    return (u + 0x7fffu + ((u >> 16) & 1u)) >> 16;
}
__device__ inline unsigned pk2(float lo, float hi) {
    return bf16rne(lo) | (bf16rne(hi) << 16);
}
union FragU { unsigned u[4]; short8 s; uint4 v; };

// ---------------- repack: W1bp + MFMA B-fragment packs ----------------
// B-frag layout (16x16x32): lane holds B[k0 + (lane>>4)*8 + j][nt*16 + (lane&15)], j=0..7
__global__ void repack_kernel(const float* __restrict__ W1, const float* __restrict__ b1,
                              const float* __restrict__ W2,
                              float* __restrict__ W1bp,
                              uint4* __restrict__ Bpack1, uint4* __restrict__ Bpack2) {
    int tid = blockIdx.x * 256 + threadIdx.x;
    if (tid < 2048) {                        // Bpack1: B[k][n] = W1[n*131 + k], K=128
        int lane = tid & 63, ent = tid >> 6; // ent = kt*8+nt, kt<4
        int n = (ent & 7) * 16 + (lane & 15);
        int k0 = (ent >> 3) * 32 + ((lane >> 4) << 3);
        const float* src = W1 + n * 131 + k0;
        FragU f;
        f.u[0] = pk2(src[0], src[1]);
        f.u[1] = pk2(src[2], src[3]);
        f.u[2] = pk2(src[4], src[5]);
        f.u[3] = pk2(src[6], src[7]);
        Bpack1[ent * 64 + lane] = f.v;
    } else if (tid < 6144) {                 // Bpack2: B[k][n] = W2[n*256 + k], K=256
        int t2 = tid - 2048;
        int lane = t2 & 63, ent = t2 >> 6;   // ent = kt*8+nt, kt<8
        int n = (ent & 7) * 16 + (lane & 15);
        int k0 = (ent >> 3) * 32 + ((lane >> 4) << 3);
        const float* src = W2 + n * 256 + k0;
        FragU f;
        f.u[0] = pk2(src[0], src[1]);
        f.u[1] = pk2(src[2], src[3]);
        f.u[2] = pk2(src[4], src[5]);
        f.u[3] = pk2(src[6], src[7]);
        Bpack2[ent * 64 + lane] = f.v;
    }
    if (tid < 128) {                         // W1bp[c] = {W1[c][128..130], b1[c]}
        W1bp[tid * 4 + 0] = W1[tid * 131 + 128];
        W1bp[tid * 4 + 1] = W1[tid * 131 + 129];
        W1bp[tid * 4 + 2] = W1[tid * 131 + 130];
        W1bp[tid * 4 + 3] = b1[tid];
    }
}

// ---------------- CSR phase A: histogram of edge_dst ----------------
__global__ void hist_kernel(const int* __restrict__ edst, int* __restrict__ counts) {
    int e = blockIdx.x * 256 + threadIdx.x;
    if (e < N_EDGES) atomicAdd(&counts[edst[e]], 1);
}

// ---------------- parallel scan, phase A ----------------
__global__ __launch_bounds__(256) void scanA_kernel(const int* __restrict__ counts,
                                                    int* __restrict__ offsets,
                                                    int* __restrict__ blockSums) {
    __shared__ int sd[256];
    const int t = threadIdx.x, b = blockIdx.x;
    const int idx = b * 256 + t;
    int v = (idx < N_NODES) ? counts[idx] : 0;
    sd[t] = v;
    __syncthreads();
    for (int off = 1; off < 256; off <<= 1) {
        int x = sd[t];
        int add = (t >= off) ? sd[t - off] : 0;
        __syncthreads();
        sd[t] = x + add;
        __syncthreads();
    }
    if (idx < N_NODES) offsets[idx] = sd[t] - v;
    if (t == 255) blockSums[b] = sd[255];
}

// ---------------- parallel scan, phase B ----------------
__global__ __launch_bounds__(256) void scanB_kernel(int* __restrict__ offsets,
                                                    const int* __restrict__ blockSums,
                                                    int* __restrict__ cursor) {
    __shared__ int sd[256];
    const int t = threadIdx.x, b = blockIdx.x;
    sd[t] = (t < SCAN_BLOCKS) ? blockSums[t] : 0;
    __syncthreads();
    for (int off = 1; off < 256; off <<= 1) {
        int x = sd[t];
        int add = (t >= off) ? sd[t - off] : 0;
        __syncthreads();
        sd[t] = x + add;
        __syncthreads();
    }
    const int prefix = (b == 0) ? 0 : sd[b - 1];
    const int idx = b * 256 + t;
    if (idx < N_NODES) {
        int o = offsets[idx] + prefix;
        offsets[idx] = o;
        cursor[idx] = o;
    }
    if (b == SCAN_BLOCKS - 1 && t == 255) offsets[N_NODES] = sd[SCAN_BLOCKS - 1];
}

// ---------------- CSR phase B: scatter 16B edge records ----------------
__global__ void build_csr_kernel(const int* __restrict__ esrc, const int* __restrict__ edst,
                                 const float* __restrict__ ew,
                                 int* __restrict__ cursor, float4* __restrict__ csr) {
    int e = blockIdx.x * 256 + threadIdx.x;
    if (e < N_EDGES) {
        int dst = edst[e];
        int pos = atomicAdd(&cursor[dst], 1);
        float4 r;
        r.x = __int_as_float(esrc[e]);
        r.y = ew[e * 3 + 0];
        r.z = ew[e * 3 + 1];
        r.w = ew[e * 3 + 2];
        csr[pos] = r;
    }
}

// ---------------- node pre-projection (MFMA): g = bf16(W1a @ h^T) ----------
// wave per 16-node tile; A built in-register from fp32 h; epilogue via LDS
// to emit packed bf16-pair layout (uint l = channels {2l, 2l+1}).
__global__ __launch_bounds__(256) void node_proj_mfma(const float* __restrict__ h,
                                                      const uint4* __restrict__ Bpack1,
                                                      unsigned* __restrict__ g) {
    __shared__ float lds[64][132];           // +4 pad: D-frag write 2-way only
    const int wave = threadIdx.x >> 6;
    const int lane = threadIdx.x & 63;
    const int T = blockIdx.x * 4 + wave;

    if (T < N_TILES) {
        f32x4 acc[8];
        #pragma unroll
        for (int i = 0; i < 8; i++) acc[i] = (f32x4)(0.f);

        const int row = T * 16 + (lane & 15);
        const float* hrow = h + row * 128 + ((lane >> 4) << 3);

        #pragma unroll
        for (int kt = 0; kt < 4; kt++) {
            float4 x0 = *(const float4*)(hrow + kt * 32);
            float4 x1 = *(const float4*)(hrow + kt * 32 + 4);
            FragU a;
            a.u[0] = pk2(x0.x, x0.y);
            a.u[1] = pk2(x0.z, x0.w);
            a.u[2] = pk2(x1.x, x1.y);
            a.u[3] = pk2(x1.z, x1.w);
            #pragma unroll
            for (int nt = 0; nt < 8; nt++) {
                FragU b;
                b.v = Bpack1[(kt * 8 + nt) * 64 + lane];
                acc[nt] = __builtin_amdgcn_mfma_f32_16x16x32_bf16(a.s, b.s, acc[nt], 0, 0, 0);
            }
        }
        // D layout: col = lane&15, row = (lane>>4)*4 + reg
        #pragma unroll
        for (int nt = 0; nt < 8; nt++) {
            #pragma unroll
            for (int reg = 0; reg < 4; reg++) {
                int r = ((lane >> 4) << 2) + reg;
                lds[wave * 16 + r][nt * 16 + (lane & 15)] = acc[nt][reg];
            }
        }
    }
    __syncthreads();

    // pack 64 nodes x 128 ch -> g (uint = bf16 pair, standard channel order)
    const int t = threadIdx.x;
    const int nodeL = t >> 2, seg = t & 3;           // seg = 32 channels
    const int gnode = blockIdx.x * 64 + nodeL;
    if (gnode < N_NODES) {
        #pragma unroll
        for (int i = 0; i < 4; i++) {                // uint4 i covers 8 channels
            float4 y0 = *(const float4*)&lds[nodeL][seg * 32 + i * 8];
            float4 y1 = *(const float4*)&lds[nodeL][seg * 32 + i * 8 + 4];
            uint4 o;
            o.x = pk2(y0.x, y0.y);
            o.y = pk2(y0.z, y0.w);
            o.z = pk2(y1.x, y1.y);
            o.w = pk2(y1.z, y1.w);
            ((uint4*)g)[gnode * 16 + seg * 4 + i] = o;
        }
    }
}

// ---------------- aggregation: wave/node, 8 concurrent gather chains ---------
#define AGG_UNROLL 8
__global__ __launch_bounds__(256) void agg_kernel(const unsigned* __restrict__ gb,
                                                  const float4* __restrict__ csr,
                                                  const int* __restrict__ offsets,
                                                  const float* __restrict__ W1bp,
                                                  float* __restrict__ hN) {
    const int wave = threadIdx.x >> 6;
    const int lane = threadIdx.x & 63;
    const int v = blockIdx.x * 4 + wave;
    if (v >= N_NODES) return;

    const int beg = offsets[v];
    const int end = offsets[v + 1];
    const float4 wb0 = ((const float4*)W1bp)[2 * lane];
    const float4 wb1 = ((const float4*)W1bp)[2 * lane + 1];

    float a0 = 0.f, a1 = 0.f;
    for (int i = beg; i < end; i += AGG_UNROLL) {
        const int n = end - i;
        float4 r[AGG_UNROLL];
        #pragma unroll
        for (int u = 0; u < AGG_UNROLL; u++) {
            int idx = i + ((u < n) ? u : 0);
            r[u] = csr[idx];
        }
        unsigned gv[AGG_UNROLL];
        #pragma unroll
        for (int u = 0; u < AGG_UNROLL; u++) {
            int src = __float_as_int(r[u].x);
            gv[u] = gb[src * 64 + lane];
        }
        #pragma unroll
        for (int u = 0; u < AGG_UNROLL; u++) {
            if (u < n) {
                float g0 = __uint_as_float(gv[u] << 16);
                float g1 = __uint_as_float(gv[u] & 0xffff0000u);
                float t0 = fmaf(wb0.x, r[u].y, g0);
                t0 = fmaf(wb0.y, r[u].z, t0);
                t0 = fmaf(wb0.z, r[u].w, t0);
                t0 += wb0.w;
                a0 += (t0 >= 0.f) ? t0 : 0.01f * t0;
                float t1 = fmaf(wb1.x, r[u].y, g1);
                t1 = fmaf(wb1.y, r[u].z, t1);
                t1 = fmaf(wb1.z, r[u].w, t1);
                t1 += wb1.w;
                a1 += (t1 >= 0.f) ? t1 : 0.01f * t1;
            }
        }
    }
    int deg = end - beg;
    float inv = 1.0f / (float)((deg > 0) ? deg : 1);
    ((float2*)hN)[v * 64 + lane] = make_float2(a0 * inv, a1 * inv);
}

// ---------------- final (MFMA): out = relu(concat(h,hN) @ W2^T + b2) --------
__global__ __launch_bounds__(256) void final_mfma(const float* __restrict__ h,
                                                  const float* __restrict__ hN,
                                                  const uint4* __restrict__ Bpack2,
                                                  const float* __restrict__ b2,
                                                  float* __restrict__ out) {
    const int wave = threadIdx.x >> 6;
    const int lane = threadIdx.x & 63;
    const int T = blockIdx.x * 4 + wave;
    if (T >= N_TILES) return;

    f32x4 acc[8];
    #pragma unroll
    for (int i = 0; i < 8; i++) acc[i] = (f32x4)(0.f);

    const int row = T * 16 + (lane & 15);
    const int koff = (lane >> 4) << 3;
    const float* hrow = h + row * 128 + koff;
    const float* nrow = hN + row * 128 + koff;

    #pragma unroll
    for (int kt = 0; kt < 8; kt++) {
        const float* src = (kt < 4) ? (hrow + kt * 32) : (nrow + (kt - 4) * 32);
        float4 x0 = *(const float4*)(src);
        float4 x1 = *(const float4*)(src + 4);
        FragU a;
        a.u[0] = pk2(x0.x, x0.y);
        a.u[1] = pk2(x0.z, x0.w);
        a.u[2] = pk2(x1.x, x1.y);
        a.u[3] = pk2(x1.z, x1.w);
        #pragma unroll
        for (int nt = 0; nt < 8; nt++) {
            FragU b;
            b.v = Bpack2[(kt * 8 + nt) * 64 + lane];
            acc[nt] = __builtin_amdgcn_mfma_f32_16x16x32_bf16(a.s, b.s, acc[nt], 0, 0, 0);
        }
    }
    // epilogue: bias + relu, D layout col=lane&15, row=(lane>>4)*4+reg
    #pragma unroll
    for (int nt = 0; nt < 8; nt++) {
        int ch = nt * 16 + (lane & 15);
        float bias = b2[ch];
        #pragma unroll
        for (int reg = 0; reg < 4; reg++) {
            int node = T * 16 + ((lane >> 4) << 2) + reg;
            out[node * 128 + ch] = fmaxf(acc[nt][reg] + bias, 0.f);
        }
    }
}

extern "C" void kernel_launch(void* const* d_in, const int* in_sizes, int n_in,
                              void* d_out, int out_size, void* d_ws, size_t ws_size,
                              hipStream_t stream) {
    const float* h    = (const float*)d_in[0];
    const int*   esrc = (const int*)d_in[1];
    const int*   edst = (const int*)d_in[2];
    const float* ew   = (const float*)d_in[3];
    const float* W1   = (const float*)d_in[4];
    const float* b1   = (const float*)d_in[5];
    const float* W2   = (const float*)d_in[6];
    const float* b2   = (const float*)d_in[7];
    float* out = (float*)d_out;
    float* ws  = (float*)d_ws;

    unsigned* g   = (unsigned*)(ws + OFF_G);
    float* hN     = ws + OFF_HN;
    float* W1bp   = ws + OFF_W1BP;
    uint4* Bpack1 = (uint4*)(ws + OFF_BP1);
    uint4* Bpack2 = (uint4*)(ws + OFF_BP2);

    // scratch carved out of d_out (fully dead before final_mfma writes out)
    float4* csr     = (float4*)((float*)d_out + DOUT_CSR);
    int*    counts  = (int*)((float*)d_out + DOUT_COUNTS);
    int*    offs    = (int*)((float*)d_out + DOUT_OFFSETS);
    int*    cursor  = (int*)((float*)d_out + DOUT_CURSOR);
    int*    blkSums = (int*)((float*)d_out + DOUT_BLKSUMS);

    // 1. repack weights (W1bp + MFMA B-frag packs)
    repack_kernel<<<24, 256, 0, stream>>>(W1, b1, W2, W1bp, Bpack1, Bpack2);

    // 2. CSR build
    hipMemsetAsync(counts, 0, (size_t)N_NODES * sizeof(int), stream);
    hist_kernel<<<(N_EDGES + 255) / 256, 256, 0, stream>>>(edst, counts);
    scanA_kernel<<<SCAN_BLOCKS, 256, 0, stream>>>(counts, offs, blkSums);
    scanB_kernel<<<SCAN_BLOCKS, 256, 0, stream>>>(offs, blkSums, cursor);
    build_csr_kernel<<<(N_EDGES + 255) / 256, 256, 0, stream>>>(esrc, edst, ew, cursor, csr);

    // 3. node pre-projection (MFMA, bf16-packed output)
    node_proj_mfma<<<(N_TILES + 3) / 4, 256, 0, stream>>>(h, Bpack1, g);

    // 4. aggregation (wave per dst, 8 gather chains in flight)
    agg_kernel<<<(N_NODES + 3) / 4, 256, 0, stream>>>(g, csr, offs, W1bp, hN);

    // 5. final fused GEMM + relu (MFMA)
    final_mfma<<<(N_TILES + 3) / 4, 256, 0, stream>>>(h, hN, Bpack2, b2, out);
}